// Round 10
// baseline (5697.777 us; speedup 1.0000x reference)
//
#include <hip/hip_runtime.h>
#include <math.h>

#define NQ     512
#define DD     27
#define NC     10
#define KK     3
#define NTHR   256
#define NSLICE 512              // feature slices == fused-kernel blocks (2/CU, co-resident)
#define NCAND  (NSLICE*3)       // 1536 candidates per query
#define CHK    64               // features per LDS chunk
#define ROWW   68               // padded chunk row (27 rows x 68 words, 272B = 16B-aligned)

static __device__ __forceinline__ unsigned fbits(float x){ return __float_as_uint(x); }

static __device__ __forceinline__ float4 fma4(float4 a, float s, float4 c){
  c.x = fmaf(a.x, s, c.x); c.y = fmaf(a.y, s, c.y);
  c.z = fmaf(a.z, s, c.z); c.w = fmaf(a.w, s, c.w);
  return c;
}

// K1: scale[d] = max |features[:,d]| (proven r2-r9, unchanged).
__global__ void k_scale(const float* __restrict__ feats, unsigned* __restrict__ scale_bits,
                        int total, int total_f4) {
  __shared__ unsigned smax[DD];
  int t = threadIdx.x;
  if (t < DD) smax[t] = 0u;
  __syncthreads();
  int gid = blockIdx.x * blockDim.x + t;
  int stride = gridDim.x * blockDim.x;       // 864*256: 4*stride ≡ 0 mod 27
  const float4* f4 = (const float4*)feats;
  float m0=0.f, m1=0.f, m2=0.f, m3=0.f;
  for (int i = gid; i < total_f4; i += stride) {
    float4 v = f4[i];
    m0 = fmaxf(m0, fabsf(v.x));
    m1 = fmaxf(m1, fabsf(v.y));
    m2 = fmaxf(m2, fabsf(v.z));
    m3 = fmaxf(m3, fabsf(v.w));
  }
  int d0 = (4*gid) % DD;
  atomicMax(&smax[d0],          fbits(m0));
  atomicMax(&smax[(d0+1)%DD],   fbits(m1));
  atomicMax(&smax[(d0+2)%DD],   fbits(m2));
  atomicMax(&smax[(d0+3)%DD],   fbits(m3));
  if (gid == 0) {
    for (int i = total_f4*4; i < total; ++i)
      atomicMax(&scale_bits[i % DD], fbits(fabsf(feats[i])));
  }
  __syncthreads();
  if (t < DD) atomicMax(&scale_bits[t], smax[t]);
}

// top-3 insert on descending score (largest score == smallest d2); strict > keeps earliest f
#define TINS0(sc, fi) do {                                                 \
    if ((sc) > u2) {                                                       \
      if ((sc) > u0)      { u2=u1;x2=x1; u1=u0;x1=x0; u0=(sc);x0=(fi); }   \
      else if ((sc) > u1) { u2=u1;x2=x1; u1=(sc);x1=(fi); }                \
      else                { u2=(sc); x2=(fi); }                            \
    }                                                                      \
  } while (0)
#define TINS1(sc, fi) do {                                                 \
    if ((sc) > v2) {                                                       \
      if ((sc) > v0)      { v2=v1;y2=y1; v1=v0;y1=y0; v0=(sc);y0=(fi); }   \
      else if ((sc) > v1) { v2=v1;y2=y1; v1=(sc);y1=(fi); }                \
      else                { v2=(sc); y2=(fi); }                            \
    }                                                                      \
  } while (0)
#define TIN4Q0(h, A, fb_) do { float sc_;                                  \
    sc_ = (h).x + (A).x; TINS0(sc_, (fb_)+0);                              \
    sc_ = (h).y + (A).y; TINS0(sc_, (fb_)+1);                              \
    sc_ = (h).z + (A).z; TINS0(sc_, (fb_)+2);                              \
    sc_ = (h).w + (A).w; TINS0(sc_, (fb_)+3);                              \
  } while (0)
#define TIN4Q1(h, A, fb_) do { float sc_;                                  \
    sc_ = (h).x + (A).x; TINS1(sc_, (fb_)+0);                              \
    sc_ = (h).y + (A).y; TINS1(sc_, (fb_)+1);                              \
    sc_ = (h).z + (A).z; TINS1(sc_, (fb_)+2);                              \
    sc_ = (h).w + (A).w; TINS1(sc_, (fb_)+3);                              \
  } while (0)

// ascending insert into (c0<=c1<=c2), tie-break smaller index (lax.top_k stability)
#define INS(vv, ii) do { \
  if ((vv) < c2 || ((vv) == c2 && (ii) < j2)) { \
    if ((vv) < c0 || ((vv) == c0 && (ii) < j0))      { c2=c1;j2=j1; c1=c0;j1=j0; c0=(vv);j0=(ii); } \
    else if ((vv) < c1 || ((vv) == c1 && (ii) < j1)) { c2=c1;j2=j1; c1=(vv);j1=(ii); } \
    else                                             { c2=(vv); j2=(ii); } \
  } \
} while (0)

// Fused: qlds build -> per-slice dim-major KNN -> grid barrier -> per-query merge.
// Dim-major tiling: persistent per-lane state = 8 float4 accumulators (GEMM-C-tile
// pattern the allocator keeps in registers), NOT query values (r2-r9 pathology:
// allocator streams >28 invariant floats through L1 = ~11TB = the 150-175us plateau).
// Per 16f-tile, per d: 2 coalesced LDS q-reads + 4 uniform b128 chunk reads + 32 FMA.
// q-side traffic amortized 16x. LDS 69.2KB -> exactly 2 blocks/CU -> 512 blocks
// co-resident -> grid barrier is safe.
__global__ __launch_bounds__(NTHR, 2) void k_fused(
    const float* __restrict__ queries, const float* __restrict__ feats,
    const float* __restrict__ labels, const unsigned* __restrict__ scale_bits,
    float* __restrict__ pd2v, int* __restrict__ pd2i,
    unsigned* __restrict__ bar, float* __restrict__ out, int nfeat) {
  __shared__ float qlds[DD*NQ];        // 55296 B  [d][q] = q*r
  __shared__ float chk[DD*ROWW];       //  7344 B  [d][fl] = f*r (transposed chunk)
  __shared__ float fnrh[ROWW];         //   272 B  -0.5*||f*r||^2 (or -inf)
  __shared__ float rs[DD];             //   108 B
  __shared__ float sk[NTHR*3];         //  3072 B  (merge)
  __shared__ int   si[NTHR*3];         //  3072 B  (merge)   total 69164 B

  int t = threadIdx.x;
  int lane = t & 63;
  int w = t >> 6;
  int slice = blockIdx.x;

  // ---- build rs + qlds (all 512 queries, scaled; coalesced global reads) ----
  if (t < DD) {
    float s = __uint_as_float(scale_bits[t]);
    rs[t] = (s == 0.f) ? 0.f : 1.f / s;
  }
  __syncthreads();
  #pragma unroll
  for (int k = 0; k < 54; ++k) {                 // 54*256 = 13824 = 512*27
    int j = t + k*NTHR;
    int qq = j / DD, d = j - qq*DD;
    qlds[d*NQ + qq] = queries[j] * rs[d];
  }
  __syncthreads();

  // ---- KNN over this block's feature slice ----
  int S = (nfeat + NSLICE - 1) / NSLICE;         // 391
  int base = slice * S;
  int cnt = nfeat - base; if (cnt > S) cnt = S; if (cnt < 0) cnt = 0;
  int sliceEnd = base + cnt;
  int nchunk = (cnt + CHK - 1) / CHK;

  int qa = w*128 + lane;                          // this lane's q0; q1 = qa+64
  float u0=-INFINITY, u1=-INFINITY, u2=-INFINITY; int x0=0x7fffffff,x1=0x7fffffff,x2=0x7fffffff;
  float v0=-INFINITY, v1=-INFINITY, v2=-INFINITY; int y0=0x7fffffff,y1=0x7fffffff,y2=0x7fffffff;
  int ntot = nfeat * DD;

  for (int c = 0; c < nchunk; ++c) {
    int cb = base + c*CHK;
    __syncthreads();                              // protect chunk buffer reuse
    int gb = cb * DD;
    #pragma unroll
    for (int k = 0; k < 7; ++k) {                 // stage 27*64=1728 elems transposed
      int idx = t + k*NTHR;
      if (idx < DD*CHK) {
        int fl = idx / DD, d = idx - fl*DD;
        int gi = gb + idx;
        float vv = (gi < ntot) ? feats[gi] * rs[d] : 0.f;
        chk[d*ROWW + fl] = vv;
      }
    }
    __syncthreads();
    if (t < CHK) {                                // per-feature -0.5*norm (or -inf)
      int f = cb + t;
      float h;
      if (f < sliceEnd) {
        float sm = 0.f;
        #pragma unroll
        for (int d = 0; d < DD; ++d) { float vv = chk[d*ROWW + t]; sm = fmaf(vv, vv, sm); }
        h = -0.5f * sm;
      } else h = -INFINITY;                       // excluded (other slice / past end)
      fnrh[t] = h;
    }
    __syncthreads();

    for (int ft = 0; ft < 4; ++ft) {              // 4 tiles of 16 features
      float4 z = {0.f,0.f,0.f,0.f};
      float4 A00=z,A01=z,A02=z,A03=z, A10=z,A11=z,A12=z,A13=z;
      #pragma unroll
      for (int d = 0; d < DD; ++d) {
        float q0v = qlds[d*NQ + qa];              // coalesced, conflict-free
        float q1v = qlds[d*NQ + qa + 64];
        const float4* lf = (const float4*)&chk[d*ROWW + ft*16];  // uniform, 16B-aligned
        float4 f0 = lf[0], f1 = lf[1], f2 = lf[2], f3 = lf[3];
        A00 = fma4(f0,q0v,A00); A01 = fma4(f1,q0v,A01);
        A02 = fma4(f2,q0v,A02); A03 = fma4(f3,q0v,A03);
        A10 = fma4(f0,q1v,A10); A11 = fma4(f1,q1v,A11);
        A12 = fma4(f2,q1v,A12); A13 = fma4(f3,q1v,A13);
      }
      const float4* fh = (const float4*)&fnrh[ft*16];
      float4 h0 = fh[0], h1 = fh[1], h2 = fh[2], h3 = fh[3];
      int fb0 = cb + ft*16;
      TIN4Q0(h0, A00, fb0+0);  TIN4Q0(h1, A01, fb0+4);
      TIN4Q0(h2, A02, fb0+8);  TIN4Q0(h3, A03, fb0+12);
      TIN4Q1(h0, A10, fb0+0);  TIN4Q1(h1, A11, fb0+4);
      TIN4Q1(h2, A12, fb0+8);  TIN4Q1(h3, A13, fb0+12);
    }
  }

  // candidate write: key = -2*score = d2 - qnorm
  {
    long o = (long)qa * NCAND + slice*3;
    pd2v[o+0] = -2.f*u0; pd2v[o+1] = -2.f*u1; pd2v[o+2] = -2.f*u2;
    pd2i[o+0] = x0;      pd2i[o+1] = x1;      pd2i[o+2] = x2;
    long o1 = (long)(qa+64) * NCAND + slice*3;
    pd2v[o1+0] = -2.f*v0; pd2v[o1+1] = -2.f*v1; pd2v[o1+2] = -2.f*v2;
    pd2i[o1+0] = y0;      pd2i[o1+1] = y1;      pd2i[o1+2] = y2;
  }

  // ---- grid barrier (512 blocks co-resident by construction) ----
  __syncthreads();
  if (t == 0) {
    __threadfence();                                    // release: drain cand stores
    unsigned arrived = atomicAdd(bar, 1u) + 1u;
    if (arrived < (unsigned)NSLICE) {
      while (atomicAdd(bar, 0u) < (unsigned)NSLICE) __builtin_amdgcn_s_sleep(8);
    }
    __threadfence();                                    // acquire
  }
  __syncthreads();

  // ---- merge phase: this block owns query q = blockIdx.x ----
  {
    int q = blockIdx.x;                                 // NSLICE == NQ == 512
    float c0=INFINITY, c1=INFINITY, c2=INFINITY;
    int   j0=0x7fffffff, j1=0x7fffffff, j2=0x7fffffff;
    const float* pv = pd2v + (long)q * NCAND;
    const int*   pi = pd2i + (long)q * NCAND;
    #pragma unroll
    for (int k = 0; k < NCAND/NTHR; ++k) {              // 6 coalesced rounds
      int i = t + k*NTHR;
      float vv = pv[i]; int ix = pi[i];
      INS(vv, ix);
    }
    sk[t*3+0]=c0; sk[t*3+1]=c1; sk[t*3+2]=c2;
    si[t*3+0]=j0; si[t*3+1]=j1; si[t*3+2]=j2;
    __syncthreads();
    if (t < 64) {
      for (int s = 1; s < 4; ++s) {
        int bb = t + s*64;
        #pragma unroll
        for (int k = 0; k < 3; ++k) { float vv = sk[bb*3+k]; int ix = si[bb*3+k]; INS(vv, ix); }
      }
      sk[t*3+0]=c0; sk[t*3+1]=c1; sk[t*3+2]=c2;
      si[t*3+0]=j0; si[t*3+1]=j1; si[t*3+2]=j2;
    }
    __syncthreads();
    if (t == 0) {
      for (int s = 1; s < 64; ++s) {
        #pragma unroll
        for (int k = 0; k < 3; ++k) { float vv = sk[s*3+k]; int ix = si[s*3+k]; INS(vv, ix); }
      }
      float qn = 0.f;                                   // qnorm from resident qlds
      #pragma unroll
      for (int d = 0; d < DD; ++d) { float vv = qlds[d*NQ + q]; qn = fmaf(vv, vv, qn); }
      float kd0 = sqrtf(fmaxf(c0 + qn, 0.f));
      float kd1 = sqrtf(fmaxf(c1 + qn, 0.f));
      float kd2 = sqrtf(fmaxf(c2 + qn, 0.f));
      const float* l0 = labels + (long)j0 * NC;
      const float* l1 = labels + (long)j1 * NC;
      const float* l2 = labels + (long)j2 * NC;
      float inv0 = 1.f / ((kd0 == 0.f) ? 1.f : kd0);
      float inv1 = 1.f / ((kd1 == 0.f) ? 1.f : kd1);
      float inv2 = 1.f / ((kd2 == 0.f) ? 1.f : kd2);
      float wv[NC];
      #pragma unroll
      for (int cc = 0; cc < NC; ++cc)
        wv[cc] = l0[cc]*inv0 + l1[cc]*inv1 + l2[cc]*inv2;
      int am = 0; float bw = wv[0];
      #pragma unroll
      for (int cc = 1; cc < NC; ++cc) if (wv[cc] > bw) { bw = wv[cc]; am = cc; }
      float* o = out + q * (KK + NC);
      o[0] = kd0; o[1] = kd1; o[2] = kd2;
      if (kd0 == 0.f) {
        #pragma unroll
        for (int cc = 0; cc < NC; ++cc) o[3+cc] = l0[cc];
      } else {
        #pragma unroll
        for (int cc = 0; cc < NC; ++cc) o[3+cc] = (cc == am) ? 1.f : 0.f;
      }
    }
  }
}

extern "C" void kernel_launch(void* const* d_in, const int* in_sizes, int n_in,
                              void* d_out, int out_size, void* d_ws, size_t ws_size,
                              hipStream_t stream) {
  const float* queries = (const float*)d_in[0];   // (512, 27)
  const float* feats   = (const float*)d_in[1];   // (200000, 27)
  const float* labels  = (const float*)d_in[2];   // (200000, 10)
  float* out = (float*)d_out;                     // (512, 13)
  char*  ws  = (char*)d_ws;

  int total = in_sizes[1];                         // 5,400,000
  int nfeat = total / DD;                          // 200,000

  unsigned* bar        = (unsigned*)ws;            // u32 @ 0 (zeroed every launch)
  unsigned* scale_bits = (unsigned*)(ws + 64);     // 27 u32 (zeroed)
  float* pd2v = (float*)(ws + (1<<20));            // [512][1536] f32 (3.15 MB)
  int*   pd2i = (int*)(ws + (5<<20));              // [512][1536] i32 (3.15 MB)

  hipMemsetAsync(ws, 0, 256, stream);              // zero barrier ctr + scale_bits
  k_scale<<<864, 256, 0, stream>>>(feats, scale_bits, total, total / 4);
  k_fused<<<NSLICE, NTHR, 0, stream>>>(queries, feats, labels, scale_bits,
                                       pd2v, pd2i, bar, out, nfeat);
}

// Round 11
// 293.989 us; speedup vs baseline: 19.3809x; 19.3809x over previous
//
#include <hip/hip_runtime.h>
#include <math.h>

#define NQ     512
#define DD     27
#define DP     28               // padded row: 27 scaled dims + (-0.5*||fs||^2); q slot27 = 1.0
#define NC     10
#define KK     3
#define NTHR   256
#define CHK    128              // features per LDS chunk
#define NBLK   512              // knn blocks (2/CU), grid-stride over chunks
#define NCAND  (NBLK*3)         // 1536 candidates per query

static __device__ __forceinline__ unsigned fbits(float x){ return __float_as_uint(x); }

// K1: scale[d] = max |features[:,d]| (proven r2-r10, unchanged).
__global__ void k_scale(const float* __restrict__ feats, unsigned* __restrict__ scale_bits,
                        int total, int total_f4) {
  __shared__ unsigned smax[DD];
  int t = threadIdx.x;
  if (t < DD) smax[t] = 0u;
  __syncthreads();
  int gid = blockIdx.x * blockDim.x + t;
  int stride = gridDim.x * blockDim.x;       // 864*256: 4*stride ≡ 0 mod 27
  const float4* f4 = (const float4*)feats;
  float m0=0.f, m1=0.f, m2=0.f, m3=0.f;
  for (int i = gid; i < total_f4; i += stride) {
    float4 v = f4[i];
    m0 = fmaxf(m0, fabsf(v.x));
    m1 = fmaxf(m1, fabsf(v.y));
    m2 = fmaxf(m2, fabsf(v.z));
    m3 = fmaxf(m3, fabsf(v.w));
  }
  int d0 = (4*gid) % DD;
  atomicMax(&smax[d0],          fbits(m0));
  atomicMax(&smax[(d0+1)%DD],   fbits(m1));
  atomicMax(&smax[(d0+2)%DD],   fbits(m2));
  atomicMax(&smax[(d0+3)%DD],   fbits(m3));
  if (gid == 0) {
    for (int i = total_f4*4; i < total; ++i)
      atomicMax(&scale_bits[i % DD], fbits(fabsf(feats[i])));
  }
  __syncthreads();
  if (t < DD) atomicMax(&scale_bits[t], smax[t]);
}

// K2: pf[f][28] = {f*r (27), -0.5*||f*r||^2}; rows in [nfeat, PFROWS) get
// {0..0, -INF} so they can never enter a top-3.  Also qp[q][28] = {q*r, 1.0}
// and qnorm.  Feature reads LDS-staged for coalescing (r7-proven).
__global__ __launch_bounds__(NTHR) void k_prepfn(
    const float* __restrict__ queries, const float* __restrict__ feats,
    const unsigned* __restrict__ scale_bits, float* __restrict__ qp,
    float* __restrict__ qnorm, float* __restrict__ pf, int nfeat, int pfrows) {
  __shared__ float rs[DD];
  __shared__ float rows[NTHR*DD];
  int t = threadIdx.x;
  if (t < DD) {
    float s = __uint_as_float(scale_bits[t]);
    rs[t] = (s == 0.f) ? 0.f : 1.f / s;
  }
  __syncthreads();
  int fbase = blockIdx.x * NTHR;
  int gbase = fbase * DD;
  int ntot  = nfeat * DD;
  #pragma unroll
  for (int j = 0; j < DD; ++j) {
    int idx = t + j*NTHR;
    int g = gbase + idx;
    rows[idx] = (g < ntot) ? feats[g] : 0.f;
  }
  __syncthreads();
  int f = fbase + t;
  if (f < pfrows) {
    float* dst = pf + (size_t)f * DP;
    if (f < nfeat) {
      float acc = 0.f;
      #pragma unroll
      for (int d = 0; d < DD; ++d) {
        float x = rows[t*DD + d] * rs[d];
        dst[d] = x;
        acc = fmaf(x, x, acc);
      }
      dst[DD] = -0.5f * acc;
    } else {
      #pragma unroll
      for (int d = 0; d < DD; ++d) dst[d] = 0.f;
      dst[DD] = -INFINITY;                       // pad row: acc = -inf, never selected
    }
  }
  if (blockIdx.x == 0) {
    for (int qq = t; qq < NQ; qq += NTHR) {
      float nrm = 0.f;
      #pragma unroll
      for (int d = 0; d < DD; ++d) {
        float v = queries[qq*DD + d] * rs[d];    // q*r (reference rounding)
        qp[qq*DP + d] = v;
        nrm = fmaf(v, v, nrm);
      }
      qp[qq*DP + DD] = 1.0f;                     // pairs with -0.5*||fs||^2
      qnorm[qq] = nrm;
    }
  }
}

// K3: r2-structure (the only round with q resident: VGPR=84, VALUBusy 82%),
// minus its measured overheads.  Block covers ALL 512 queries (2/thread: t and
// t+256); grid-strides over 1563 chunks of 128 prescaled rows.  Staging is a
// pure float4 copy (no div/mod, no scaling, 1 barrier pair per chunk; norm is
// packed in slot 27).  Hot loop per feature: 7 uniform (broadcast) b128 LDS
// reads + 56 FMA + 2 top-3 inserts.  Partials: [blk][q][3] contiguous stores.
__global__ __launch_bounds__(NTHR) void k_knn(
    const float4* __restrict__ pf4, const float* __restrict__ qp,
    float* __restrict__ pdv, int* __restrict__ pdi, int nchunk) {
  __shared__ float4 chk4[CHK*7];                 // 14336 B
  int t = threadIdx.x;

  float q0[DP], q1[DP];
  #pragma unroll
  for (int d = 0; d < DP; ++d) {
    q0[d] = qp[t*DP + d];
    q1[d] = qp[(t+NTHR)*DP + d];
  }

  float s00=-INFINITY, s01=-INFINITY, s02=-INFINITY;
  float s10=-INFINITY, s11=-INFINITY, s12=-INFINITY;
  int   i00=0x7fffffff, i01=0x7fffffff, i02=0x7fffffff;
  int   i10=0x7fffffff, i11=0x7fffffff, i12=0x7fffffff;

  for (int c = blockIdx.x; c < nchunk; c += NBLK) {
    __syncthreads();
    const float4* src = pf4 + (size_t)c * (CHK*7);
    #pragma unroll
    for (int k = 0; k < (CHK*7)/NTHR; ++k)       // 896/256 = 3.5 -> 3 full + tail
      chk4[t + k*NTHR] = src[t + k*NTHR];
    if (t < (CHK*7) - ((CHK*7)/NTHR)*NTHR + NTHR) { // last partial round (128 threads)
      int idx = t + ((CHK*7)/NTHR)*NTHR;
      if (idx < CHK*7) chk4[idx] = src[idx];
    }
    __syncthreads();

    #pragma unroll 2
    for (int f = 0; f < CHK; ++f) {
      const float4* lf = &chk4[f*7];             // uniform address -> broadcast
      float a0a=0.f, a0b=0.f, a1a=0.f, a1b=0.f;
      #pragma unroll
      for (int j = 0; j < 7; ++j) {
        float4 v = lf[j];
        if ((j & 1) == 0) {
          a0a = fmaf(v.x, q0[4*j+0], a0a);
          a0a = fmaf(v.y, q0[4*j+1], a0a);
          a0a = fmaf(v.z, q0[4*j+2], a0a);
          a0a = fmaf(v.w, q0[4*j+3], a0a);
          a1a = fmaf(v.x, q1[4*j+0], a1a);
          a1a = fmaf(v.y, q1[4*j+1], a1a);
          a1a = fmaf(v.z, q1[4*j+2], a1a);
          a1a = fmaf(v.w, q1[4*j+3], a1a);
        } else {
          a0b = fmaf(v.x, q0[4*j+0], a0b);
          a0b = fmaf(v.y, q0[4*j+1], a0b);
          a0b = fmaf(v.z, q0[4*j+2], a0b);
          a0b = fmaf(v.w, q0[4*j+3], a0b);
          a1b = fmaf(v.x, q1[4*j+0], a1b);
          a1b = fmaf(v.y, q1[4*j+1], a1b);
          a1b = fmaf(v.z, q1[4*j+2], a1b);
          a1b = fmaf(v.w, q1[4*j+3], a1b);
        }
      }
      float acc0 = a0a + a0b;                    // includes -0.5||fs||^2 (slot 27)
      float acc1 = a1a + a1b;
      int fi = c*CHK + f;
      if (acc0 > s02) {
        if (acc0 > s00)      { s02=s01;i02=i01; s01=s00;i01=i00; s00=acc0;i00=fi; }
        else if (acc0 > s01) { s02=s01;i02=i01; s01=acc0;i01=fi; }
        else                 { s02=acc0; i02=fi; }
      }
      if (acc1 > s12) {
        if (acc1 > s10)      { s12=s11;i12=i11; s11=s10;i11=i10; s10=acc1;i10=fi; }
        else if (acc1 > s11) { s12=s11;i12=i11; s11=acc1;i11=fi; }
        else                 { s12=acc1; i12=fi; }
      }
    }
  }

  // block-contiguous partial write: [blk][q][3], key = -2*acc = d2 - qnorm
  long ob = (long)blockIdx.x * NQ * 3;
  long o0 = ob + (long)t * 3;
  pdv[o0+0] = -2.f*s00; pdv[o0+1] = -2.f*s01; pdv[o0+2] = -2.f*s02;
  pdi[o0+0] = i00;      pdi[o0+1] = i01;      pdi[o0+2] = i02;
  long o1 = ob + (long)(t+NTHR) * 3;
  pdv[o1+0] = -2.f*s10; pdv[o1+1] = -2.f*s11; pdv[o1+2] = -2.f*s12;
  pdi[o1+0] = i10;      pdi[o1+1] = i11;      pdi[o1+2] = i12;
}

// ascending insert into (c0<=c1<=c2), tie-break smaller index (lax.top_k stability)
#define INS(vv, ii) do { \
  if ((vv) < c2 || ((vv) == c2 && (ii) < j2)) { \
    if ((vv) < c0 || ((vv) == c0 && (ii) < j0))      { c2=c1;j2=j1; c1=c0;j1=j0; c0=(vv);j0=(ii); } \
    else if ((vv) < c1 || ((vv) == c1 && (ii) < j1)) { c2=c1;j2=j1; c1=(vv);j1=(ii); } \
    else                                             { c2=(vv); j2=(ii); } \
  } \
} while (0)

// K4: one block per query — merge NBLK*3 candidates ([blk][q][3] layout), epilogue.
__global__ __launch_bounds__(NTHR) void k_merge(
    const float* __restrict__ pdv, const int* __restrict__ pdi,
    const float* __restrict__ qnorm, const float* __restrict__ labels,
    float* __restrict__ out) {
  __shared__ float sk[NTHR*3];
  __shared__ int   si[NTHR*3];
  int q = blockIdx.x, t = threadIdx.x;
  float c0=INFINITY, c1=INFINITY, c2=INFINITY;
  int   j0=0x7fffffff, j1=0x7fffffff, j2=0x7fffffff;
  for (int b = t; b < NBLK; b += NTHR) {
    long o = ((long)b * NQ + q) * 3;
    #pragma unroll
    for (int k = 0; k < 3; ++k) { float v = pdv[o+k]; int ix = pdi[o+k]; INS(v, ix); }
  }
  sk[t*3+0]=c0; sk[t*3+1]=c1; sk[t*3+2]=c2;
  si[t*3+0]=j0; si[t*3+1]=j1; si[t*3+2]=j2;
  __syncthreads();
  if (t < 64) {
    for (int s = 1; s < 4; ++s) {
      int bb = t + s*64;
      #pragma unroll
      for (int k = 0; k < 3; ++k) { float v = sk[bb*3+k]; int ix = si[bb*3+k]; INS(v, ix); }
    }
    sk[t*3+0]=c0; sk[t*3+1]=c1; sk[t*3+2]=c2;
    si[t*3+0]=j0; si[t*3+1]=j1; si[t*3+2]=j2;
  }
  __syncthreads();
  if (t == 0) {
    for (int s = 1; s < 64; ++s) {
      #pragma unroll
      for (int k = 0; k < 3; ++k) { float v = sk[s*3+k]; int ix = si[s*3+k]; INS(v, ix); }
    }
    float qn = qnorm[q];
    float kd0 = sqrtf(fmaxf(c0 + qn, 0.f));
    float kd1 = sqrtf(fmaxf(c1 + qn, 0.f));
    float kd2 = sqrtf(fmaxf(c2 + qn, 0.f));
    const float* l0 = labels + (long)j0 * NC;
    const float* l1 = labels + (long)j1 * NC;
    const float* l2 = labels + (long)j2 * NC;
    float inv0 = 1.f / ((kd0 == 0.f) ? 1.f : kd0);
    float inv1 = 1.f / ((kd1 == 0.f) ? 1.f : kd1);
    float inv2 = 1.f / ((kd2 == 0.f) ? 1.f : kd2);
    float wv[NC];
    #pragma unroll
    for (int cc = 0; cc < NC; ++cc)
      wv[cc] = l0[cc]*inv0 + l1[cc]*inv1 + l2[cc]*inv2;
    int am = 0; float bw = wv[0];
    #pragma unroll
    for (int cc = 1; cc < NC; ++cc) if (wv[cc] > bw) { bw = wv[cc]; am = cc; }
    float* o = out + q * (KK + NC);
    o[0] = kd0; o[1] = kd1; o[2] = kd2;
    if (kd0 == 0.f) {
      #pragma unroll
      for (int cc = 0; cc < NC; ++cc) o[3+cc] = l0[cc];
    } else {
      #pragma unroll
      for (int cc = 0; cc < NC; ++cc) o[3+cc] = (cc == am) ? 1.f : 0.f;
    }
  }
}

extern "C" void kernel_launch(void* const* d_in, const int* in_sizes, int n_in,
                              void* d_out, int out_size, void* d_ws, size_t ws_size,
                              hipStream_t stream) {
  const float* queries = (const float*)d_in[0];   // (512, 27)
  const float* feats   = (const float*)d_in[1];   // (200000, 27)
  const float* labels  = (const float*)d_in[2];   // (200000, 10)
  float* out = (float*)d_out;                     // (512, 13)
  char*  ws  = (char*)d_ws;

  int total = in_sizes[1];                         // 5,400,000
  int nfeat = total / DD;                          // 200,000
  int nchunk = (nfeat + CHK - 1) / CHK;            // 1563
  int pfrows = nchunk * CHK;                       // 200,064 (chunk-padded)

  unsigned* scale_bits = (unsigned*)ws;            // 27 u32 @ 0 (zeroed)
  float* qnorm = (float*)(ws + 512);               // 512 f32
  float* qp    = (float*)(ws + 4096);              // 512*28 f32 (57 KB, 16B-aligned)
  float* pdv   = (float*)(ws + 65536);             // [512][512][3] f32 (3.15 MB)
  int*   pdi   = (int*)(ws + 3276800);             // [512][512][3] i32 (3.15 MB)
  float* pf    = (float*)(ws + 6553600);           // [200064][28] f32 (22.4 MB, 16B-aligned)

  hipMemsetAsync(ws, 0, 128, stream);              // zero scale_bits
  k_scale<<<864, 256, 0, stream>>>(feats, scale_bits, total, total / 4);
  k_prepfn<<<(pfrows + NTHR - 1) / NTHR, NTHR, 0, stream>>>(queries, feats, scale_bits,
                                                            qp, qnorm, pf, nfeat, pfrows);
  k_knn  <<<NBLK, NTHR, 0, stream>>>((const float4*)pf, qp, pdv, pdi, nchunk);
  k_merge<<<NQ, NTHR, 0, stream>>>(pdv, pdi, qnorm, labels, out);
}